// Round 11
// baseline (712.833 us; speedup 1.0000x reference)
//
#include <hip/hip_runtime.h>
#include <hip/hip_bf16.h>
#include <stdint.h>

// ---------------------------------------------------------------------------
// GIN forward, round 11: PERSISTENT fused MLP (768 resident blocks loop over
// M-tiles; LDS allocated once per block, not per tile) + high-occupancy
// standalone aggz + register-tiled 32x32x16 MFMA + radix CSR build.
// ---------------------------------------------------------------------------

typedef __attribute__((ext_vector_type(8))) short short8;
typedef __attribute__((ext_vector_type(16))) float float16v;

#define BKT 512       // nodes per bucket (dst >> 9)
#define NBMAX 256     // max buckets held in LDS (NB = 196 here)

__device__ __forceinline__ float b2f_lo(unsigned int u) {
    return __uint_as_float(u << 16);
}
__device__ __forceinline__ float b2f_hi(unsigned int u) {
    return __uint_as_float(u & 0xffff0000u);
}
__device__ __forceinline__ unsigned short f2b(float f) {
    unsigned int u = __float_as_uint(f);
    return (unsigned short)((u + 0x7fffu + ((u >> 16) & 1u)) >> 16);  // RNE
}

// ---------------- edge-index dtype detection ----------------
__global__ void detect_i64_kernel(const unsigned int* ei, int* flag) {
    if (threadIdx.x == 0) {
        int is64 = 1;
        for (int e = 0; e < 64; ++e)
            if (ei[2 * e + 1] != 0u) { is64 = 0; break; }
        *flag = is64;
    }
}

__device__ __forceinline__ int edge_at(const int* ei32, int is64, long long pos) {
    if (is64) return (int)(((const long long*)ei32)[pos]);
    return ei32[pos];
}

// ---------------- radix partition pass 1 ----------------
__global__ __launch_bounds__(256) void part_hist_kernel(
        const int* __restrict__ ei, const int* __restrict__ flag,
        int* __restrict__ bh, int E, int NB, int PB) {
    __shared__ int h[NBMAX];
    const int g = blockIdx.x, tid = threadIdx.x;
    const int is64 = *flag;
    for (int i = tid; i < NB; i += 256) h[i] = 0;
    __syncthreads();
    const int e0 = g * PB, e1 = min(e0 + PB, E);
    for (int e = e0 + tid; e < e1; e += 256) {
        int d = edge_at(ei, is64, (long long)E + e);
        atomicAdd(&h[d >> 9], 1);
    }
    __syncthreads();
    for (int i = tid; i < NB; i += 256) bh[i * gridDim.x + g] = h[i];
}

// ---------------- generic multi-block exclusive scan ----------------
__global__ __launch_bounds__(1024) void scan1_kernel(
        const int* __restrict__ in, int* __restrict__ out,
        int* __restrict__ partial, int n) {
    __shared__ int sm[1024];
    const int t = threadIdx.x;
    const int i = blockIdx.x * 1024 + t;
    int v = (i < n) ? in[i] : 0;
    sm[t] = v;
    __syncthreads();
#pragma unroll
    for (int off = 1; off < 1024; off <<= 1) {
        int x = (t >= off) ? sm[t - off] : 0;
        __syncthreads();
        sm[t] += x;
        __syncthreads();
    }
    if (i < n) out[i] = sm[t] - v;
    if (t == 1023) partial[blockIdx.x] = sm[1023];
}

__global__ __launch_bounds__(256) void scan2_kernel(
        int* __restrict__ partial, int* __restrict__ blockoff, int g1) {
    __shared__ int sm[256];
    const int t = threadIdx.x;
    int v = (t < g1) ? partial[t] : 0;
    sm[t] = v;
    __syncthreads();
#pragma unroll
    for (int off = 1; off < 256; off <<= 1) {
        int x = (t >= off) ? sm[t - off] : 0;
        __syncthreads();
        sm[t] += x;
        __syncthreads();
    }
    blockoff[t] = sm[t] - v;
}

__global__ __launch_bounds__(1024) void scan3g_kernel(
        int* __restrict__ a, const int* __restrict__ blockoff, int n) {
    int i = blockIdx.x * 1024 + threadIdx.x;
    if (i < n) a[i] += blockoff[blockIdx.x];
}

// ---------------- pass 2: scatter into bucket-contiguous staging ----------------
__global__ __launch_bounds__(256) void part_scatter_kernel(
        const int* __restrict__ ei, const int* __restrict__ flag,
        const int* __restrict__ bhs, unsigned int* __restrict__ staged,
        int E, int NB, int PB) {
    __shared__ int cur[NBMAX];
    const int g = blockIdx.x, tid = threadIdx.x;
    const int is64 = *flag;
    for (int i = tid; i < NB; i += 256) cur[i] = bhs[i * gridDim.x + g];
    __syncthreads();
    const int e0 = g * PB, e1 = min(e0 + PB, E);
    for (int e = e0 + tid; e < e1; e += 256) {
        int d = edge_at(ei, is64, (long long)E + e);
        int s = edge_at(ei, is64, (long long)e);
        int b = d >> 9;
        int p = atomicAdd(&cur[b], 1);
        staged[p] = ((unsigned int)(d & (BKT - 1)) << 17) | (unsigned int)s;
    }
}

// ---------------- pass 3: per-bucket counting sort -> offs + csr ----------------
__global__ __launch_bounds__(256) void csr_local_kernel(
        const unsigned int* __restrict__ staged, const int* __restrict__ bhs,
        int* __restrict__ offs, int* __restrict__ csr, int N, int E, int NB, int G2) {
    __shared__ int hist[BKT];
    __shared__ int cur[BKT];
    const int b = blockIdx.x;
    const int tid = threadIdx.x;
    const int start = bhs[b * G2];
    const int end = (b + 1 < NB) ? bhs[(b + 1) * G2] : E;
    const int node0 = b * BKT;
    for (int i = tid; i < BKT; i += 256) hist[i] = 0;
    __syncthreads();
    for (int i = start + tid; i < end; i += 256)
        atomicAdd(&hist[staged[i] >> 17], 1);
    __syncthreads();
    const int i0 = tid * 2, i1 = i0 + 1;
    for (int off = 1; off < BKT; off <<= 1) {
        int v0 = (i0 >= off) ? hist[i0 - off] : 0;
        int v1 = (i1 >= off) ? hist[i1 - off] : 0;
        __syncthreads();
        hist[i0] += v0;
        hist[i1] += v1;
        __syncthreads();
    }
    for (int i = tid; i < BKT; i += 256) {
        int node = node0 + i;
        if (node < N) {
            int e0 = start + ((i == 0) ? 0 : hist[i - 1]);
            offs[node] = e0;
            cur[i] = e0;
        }
    }
    if (b == NB - 1 && tid == 0) offs[N] = E;
    __syncthreads();
    for (int i = start + tid; i < end; i += 256) {
        unsigned int v = staged[i];
        int dl = v >> 17;
        int src = (int)(v & 0x1ffff);
        int p = atomicAdd(&cur[dl], 1);
        csr[p] = src;
    }
}

// ---------------- fused weight pack (32x32x16 B-fragments), 7 weights ----------------
struct PW { const float* W; unsigned short* o; int K; int KOUT; };
struct PWAll { PW d[7]; int cum[8]; };

__global__ __launch_bounds__(256) void packall_kernel(PWAll P) {
    int id = blockIdx.x * blockDim.x + threadIdx.x;
    if (id >= P.cum[7]) return;
    int w = 0;
#pragma unroll
    for (int k = 1; k < 7; ++k) w += (id >= P.cum[k]);
    const int local = id - P.cum[w];
    const float* W = P.d[w].W;
    unsigned short* out = P.d[w].o;
    const int K = P.d[w].K, KOUT = P.d[w].KOUT;
    const int KS = K / 16;
    const int l = local & 63;
    const int s = (local >> 6) % KS;
    const int T = local / (KS * 64);
    const int kbase = s * 16 + ((l >> 5) << 3);
    const int n = T * 32 + (l & 31);
#pragma unroll
    for (int j = 0; j < 8; ++j)
        out[(long long)local * 8 + j] = f2b(W[(long long)(kbase + j) * KOUT + n]);
}

// ---------------- embed: H = x(f32) @ W_embed ----------------
__global__ __launch_bounds__(256) void mm_embed(
        const float* __restrict__ X, const unsigned short* __restrict__ Wp,
        unsigned short* __restrict__ out, int Mreal) {
    constexpr int KS = 4;
    const int tid = threadIdx.x;
    const int w = tid >> 6;
    const int l = tid & 63;
    const int lm = l & 31;
    const int lk = l >> 5;
    const int wr = w & 1, wc = w >> 1;
    const long long R0 = (long long)blockIdx.x * 128 + wr * 64;
    const int T0 = (wc * 64) >> 5;

    const long long r0 = (R0 + lm < Mreal) ? (R0 + lm) : (Mreal - 1);
    const long long r1 = (R0 + 32 + lm < Mreal) ? (R0 + 32 + lm) : (Mreal - 1);
    const float* xr0 = X + r0 * 64 + lk * 8;
    const float* xr1 = X + r1 * 64 + lk * 8;
    const unsigned short* bb0 = Wp + ((long long)T0 * KS * 64 + l) * 8;
    const unsigned short* bb1 = Wp + ((long long)(T0 + 1) * KS * 64 + l) * 8;

    float16v acc00 = {}, acc01 = {}, acc10 = {}, acc11 = {};
#pragma unroll
    for (int s = 0; s < KS; ++s) {
        float4 f0a = *(const float4*)(xr0 + s * 16);
        float4 f0b = *(const float4*)(xr0 + s * 16 + 4);
        float4 f1a = *(const float4*)(xr1 + s * 16);
        float4 f1b = *(const float4*)(xr1 + s * 16 + 4);
        short8 a0, a1;
        a0[0] = (short)f2b(f0a.x); a0[1] = (short)f2b(f0a.y);
        a0[2] = (short)f2b(f0a.z); a0[3] = (short)f2b(f0a.w);
        a0[4] = (short)f2b(f0b.x); a0[5] = (short)f2b(f0b.y);
        a0[6] = (short)f2b(f0b.z); a0[7] = (short)f2b(f0b.w);
        a1[0] = (short)f2b(f1a.x); a1[1] = (short)f2b(f1a.y);
        a1[2] = (short)f2b(f1a.z); a1[3] = (short)f2b(f1a.w);
        a1[4] = (short)f2b(f1b.x); a1[5] = (short)f2b(f1b.y);
        a1[6] = (short)f2b(f1b.z); a1[7] = (short)f2b(f1b.w);
        short8 b0 = *(const short8*)(bb0 + (long long)s * 64 * 8);
        short8 b1 = *(const short8*)(bb1 + (long long)s * 64 * 8);
        acc00 = __builtin_amdgcn_mfma_f32_32x32x16_bf16(a0, b0, acc00, 0, 0, 0);
        acc01 = __builtin_amdgcn_mfma_f32_32x32x16_bf16(a0, b1, acc01, 0, 0, 0);
        acc10 = __builtin_amdgcn_mfma_f32_32x32x16_bf16(a1, b0, acc10, 0, 0, 0);
        acc11 = __builtin_amdgcn_mfma_f32_32x32x16_bf16(a1, b1, acc11, 0, 0, 0);
    }
    auto st = [&](float16v acc, long long rb, int col) {
#pragma unroll
        for (int r = 0; r < 16; ++r) {
            long long row = rb + (r & 3) + 8 * (r >> 2);
            out[row * 128 + col] = f2b(acc[r]);
        }
    };
    const long long rbase = R0 + 4 * lk;
    st(acc00, rbase,      wc * 64 + lm);
    st(acc01, rbase,      wc * 64 + 32 + lm);
    st(acc10, rbase + 32, wc * 64 + lm);
    st(acc11, rbase + 32, wc * 64 + 32 + lm);
}

// ---------------- aggregation (standalone, high occupancy) ----------------
__global__ __launch_bounds__(256) void aggz_kernel(
        const unsigned short* __restrict__ H, const int* __restrict__ offs,
        const int* __restrict__ csr, const float* __restrict__ eps,
        unsigned short* __restrict__ Z, int n) {
    const int node = blockIdx.x * 16 + (threadIdx.x >> 4);
    const int c8 = (threadIdx.x & 15) << 3;
    if (node >= n) return;
    const int beg = offs[node];
    const int end = offs[node + 1];
    float a0 = 0.f, a1 = 0.f, a2 = 0.f, a3 = 0.f;
    float a4 = 0.f, a5 = 0.f, a6 = 0.f, a7 = 0.f;
    int i = beg;
    for (; i + 3 < end; i += 4) {
        const int j0 = csr[i], j1 = csr[i + 1], j2 = csr[i + 2], j3 = csr[i + 3];
        const uint4 u0 = *(const uint4*)(H + ((long long)j0 << 7) + c8);
        const uint4 u1 = *(const uint4*)(H + ((long long)j1 << 7) + c8);
        const uint4 u2 = *(const uint4*)(H + ((long long)j2 << 7) + c8);
        const uint4 u3 = *(const uint4*)(H + ((long long)j3 << 7) + c8);
        a0 += (b2f_lo(u0.x) + b2f_lo(u1.x)) + (b2f_lo(u2.x) + b2f_lo(u3.x));
        a1 += (b2f_hi(u0.x) + b2f_hi(u1.x)) + (b2f_hi(u2.x) + b2f_hi(u3.x));
        a2 += (b2f_lo(u0.y) + b2f_lo(u1.y)) + (b2f_lo(u2.y) + b2f_lo(u3.y));
        a3 += (b2f_hi(u0.y) + b2f_hi(u1.y)) + (b2f_hi(u2.y) + b2f_hi(u3.y));
        a4 += (b2f_lo(u0.z) + b2f_lo(u1.z)) + (b2f_lo(u2.z) + b2f_lo(u3.z));
        a5 += (b2f_hi(u0.z) + b2f_hi(u1.z)) + (b2f_hi(u2.z) + b2f_hi(u3.z));
        a6 += (b2f_lo(u0.w) + b2f_lo(u1.w)) + (b2f_lo(u2.w) + b2f_lo(u3.w));
        a7 += (b2f_hi(u0.w) + b2f_hi(u1.w)) + (b2f_hi(u2.w) + b2f_hi(u3.w));
    }
    for (; i < end; ++i) {
        const uint4 u0 = *(const uint4*)(H + ((long long)csr[i] << 7) + c8);
        a0 += b2f_lo(u0.x); a1 += b2f_hi(u0.x);
        a2 += b2f_lo(u0.y); a3 += b2f_hi(u0.y);
        a4 += b2f_lo(u0.z); a5 += b2f_hi(u0.z);
        a6 += b2f_lo(u0.w); a7 += b2f_hi(u0.w);
    }
    const uint4 uh = *(const uint4*)(H + ((long long)node << 7) + c8);
    const float e = 1.0f + eps[0];
    a0 = fmaf(e, b2f_lo(uh.x), a0); a1 = fmaf(e, b2f_hi(uh.x), a1);
    a2 = fmaf(e, b2f_lo(uh.y), a2); a3 = fmaf(e, b2f_hi(uh.y), a3);
    a4 = fmaf(e, b2f_lo(uh.z), a4); a5 = fmaf(e, b2f_hi(uh.z), a5);
    a6 = fmaf(e, b2f_lo(uh.w), a6); a7 = fmaf(e, b2f_hi(uh.w), a7);
    uint4 o;
    o.x = ((unsigned int)f2b(a1) << 16) | (unsigned int)f2b(a0);
    o.y = ((unsigned int)f2b(a3) << 16) | (unsigned int)f2b(a2);
    o.z = ((unsigned int)f2b(a5) << 16) | (unsigned int)f2b(a4);
    o.w = ((unsigned int)f2b(a7) << 16) | (unsigned int)f2b(a6);
    *(uint4*)(Z + ((long long)node << 7) + c8) = o;
}

// ---------------- PERSISTENT fused MLP ----------------
// Grid = 768 blocks (3/CU resident, pinned by __launch_bounds__(256,3));
// each block loops over M-tiles (grid-stride). LDS (32 KB T tile) is
// allocated once per resident block — avoids per-tile WG launch/LDS churn.
template<int KMID, bool RELU2, bool OUTF32>
__global__ __launch_bounds__(256, 3) void fused_mlp(
        const unsigned short* __restrict__ Zin,
        const unsigned short* __restrict__ Wap, const float* __restrict__ ba,
        const unsigned short* __restrict__ Wbp, const float* __restrict__ bb,
        void* __restrict__ outp, int Mreal, int ntiles) {
    __shared__ unsigned short lds[16384];   // 32 KB: T tile, 2048 slots x 16 B
    const int tid = threadIdx.x;
    const int w = tid >> 6;
    const int l = tid & 63;
    const int lm = l & 31;
    const int lk = l >> 5;
    const int wr = w & 1, wc = w >> 1;
    constexpr int KS1 = 8;            // KIN = 128
    constexpr int KSB = KMID / 16;    // Wb K-steps (total)
    constexpr int NH = KMID / 128;    // halves

    for (int tile = blockIdx.x; tile < ntiles; tile += gridDim.x) {
        const long long R0 = (long long)tile * 128;
        const unsigned short* arow0 = Zin + (R0 + wr * 64 + lm) * 128 + lk * 8;
        const unsigned short* arow1 = arow0 + 32 * 128;

        float16v d00 = {}, d01 = {}, d10 = {}, d11 = {};

        for (int h = 0; h < NH; ++h) {
            __syncthreads();   // LDS reuse guard (prev half / prev tile reads done)

            // stage 1: Z @ Wa (cols h*128 + wc*64 .. +64), bias+relu -> T in LDS
            {
                float16v c00 = {}, c01 = {}, c10 = {}, c11 = {};
                const int T1 = (wc * 64 + h * 128) >> 5;
                const unsigned short* bp0 = Wap + ((long long)T1 * KS1 * 64 + l) * 8;
                const unsigned short* bp1 = Wap + ((long long)(T1 + 1) * KS1 * 64 + l) * 8;
#pragma unroll
                for (int s = 0; s < KS1; ++s) {
                    short8 a0 = *(const short8*)(arow0 + s * 16);
                    short8 a1 = *(const short8*)(arow1 + s * 16);
                    short8 b0 = *(const short8*)(bp0 + (long long)s * 64 * 8);
                    short8 b1 = *(const short8*)(bp1 + (long long)s * 64 * 8);
                    c00 = __builtin_amdgcn_mfma_f32_32x32x16_bf16(a0, b0, c00, 0, 0, 0);
                    c01 = __builtin_amdgcn_mfma_f32_32x32x16_bf16(a0, b1, c01, 0, 0, 0);
                    c10 = __builtin_amdgcn_mfma_f32_32x32x16_bf16(a1, b0, c10, 0, 0, 0);
                    c11 = __builtin_amdgcn_mfma_f32_32x32x16_bf16(a1, b1, c11, 0, 0, 0);
                }
                auto wT = [&](float16v acc, int rbase, int cl) {
                    const float bv = ba[h * 128 + cl];
                    const int secT = cl >> 3;
                    const int cj = cl & 7;
#pragma unroll
                    for (int r = 0; r < 16; ++r) {
                        float v = fmaxf(acc[r] + bv, 0.f);
                        const int row = rbase + (r & 3) + 8 * (r >> 2);
                        lds[(secT * 128 + (row ^ (secT & 7))) * 8 + cj] = f2b(v);
                    }
                };
                wT(c00, wr * 64 + 4 * lk,      wc * 64 + lm);
                wT(c01, wr * 64 + 4 * lk,      wc * 64 + 32 + lm);
                wT(c10, wr * 64 + 32 + 4 * lk, wc * 64 + lm);
                wT(c11, wr * 64 + 32 + 4 * lk, wc * 64 + 32 + lm);
            }
            __syncthreads();

            // stage 2: T @ Wb (k = h*128 .. +128), accumulate
            {
                const int T2 = (wc * 64) >> 5;
                const unsigned short* bp0 = Wbp + ((long long)T2 * KSB * 64 + l) * 8;
                const unsigned short* bp1 = Wbp + ((long long)(T2 + 1) * KSB * 64 + l) * 8;
#pragma unroll
                for (int s = 0; s < 8; ++s) {
                    const int sec = s * 2 + lk;
                    short8 a0 = *(const short8*)&lds[(sec * 128 + ((wr * 64 + lm) ^ (sec & 7))) * 8];
                    short8 a1 = *(const short8*)&lds[(sec * 128 + ((wr * 64 + 32 + lm) ^ (sec & 7))) * 8];
                    short8 b0 = *(const short8*)(bp0 + (long long)(h * 8 + s) * 64 * 8);
                    short8 b1 = *(const short8*)(bp1 + (long long)(h * 8 + s) * 64 * 8);
                    d00 = __builtin_amdgcn_mfma_f32_32x32x16_bf16(a0, b0, d00, 0, 0, 0);
                    d01 = __builtin_amdgcn_mfma_f32_32x32x16_bf16(a0, b1, d01, 0, 0, 0);
                    d10 = __builtin_amdgcn_mfma_f32_32x32x16_bf16(a1, b0, d10, 0, 0, 0);
                    d11 = __builtin_amdgcn_mfma_f32_32x32x16_bf16(a1, b1, d11, 0, 0, 0);
                }
            }
        }

        auto st = [&](float16v acc, int rbase, int col) {
            const float bv = bb[col];
#pragma unroll
            for (int r = 0; r < 16; ++r) {
                float v = acc[r] + bv;
                if (RELU2) v = fmaxf(v, 0.f);
                const long long row = R0 + rbase + (r & 3) + 8 * (r >> 2);
                if (OUTF32) {
                    if (row < Mreal) ((float*)outp)[row * 128 + col] = v;
                } else {
                    ((unsigned short*)outp)[row * 128 + col] = f2b(v);
                }
            }
        };
        st(d00, wr * 64 + 4 * lk,      wc * 64 + lm);
        st(d01, wr * 64 + 4 * lk,      wc * 64 + 32 + lm);
        st(d10, wr * 64 + 32 + 4 * lk, wc * 64 + lm);
        st(d11, wr * 64 + 32 + 4 * lk, wc * 64 + 32 + lm);
    }
}

extern "C" void kernel_launch(void* const* d_in, const int* in_sizes, int n_in,
                              void* d_out, int out_size, void* d_ws, size_t ws_size,
                              hipStream_t stream) {
    const float* x    = (const float*)d_in[0];
    const int*   ei   = (const int*)d_in[1];
    const float* Wemb = (const float*)d_in[2];
    const float* eps1 = (const float*)d_in[3];
    const float* w1a  = (const float*)d_in[4];
    const float* b1a  = (const float*)d_in[5];
    const float* w1b  = (const float*)d_in[6];
    const float* b1b  = (const float*)d_in[7];
    const float* eps2 = (const float*)d_in[8];
    const float* w2a  = (const float*)d_in[9];
    const float* b2a  = (const float*)d_in[10];
    const float* w2b  = (const float*)d_in[11];
    const float* b2b  = (const float*)d_in[12];
    const float* eps3 = (const float*)d_in[13];
    const float* w3a  = (const float*)d_in[14];
    const float* b3a  = (const float*)d_in[15];
    const float* w3b  = (const float*)d_in[16];
    const float* b3b  = (const float*)d_in[17];

    const int N = in_sizes[0] / 64;   // 100000
    const int E = in_sizes[1] / 2;    // 1600000
    const int Mpad = ((N + 127) / 128) * 128;  // 100096
    const int NB = (N + BKT - 1) / BKT;   // 196
    const int G2 = 1024;
    const int PB = (E + G2 - 1) / G2;
    const int BH = NB * G2;

    char* ws = (char*)d_ws;
    size_t off = 0;
    auto alloc = [&](size_t bytes) -> void* {
        void* p = ws + off;
        off = (off + bytes + 255) & ~(size_t)255;
        return p;
    };
    unsigned short* Ha  = (unsigned short*)alloc((size_t)Mpad * 128 * 2);
    unsigned short* Hb2 = (unsigned short*)alloc((size_t)Mpad * 128 * 2);
    unsigned short* Zb  = (unsigned short*)alloc((size_t)Mpad * 128 * 2);
    unsigned short* pWe = (unsigned short*)alloc((size_t)64 * 128 * 2);
    unsigned short* p1a = (unsigned short*)alloc((size_t)128 * 128 * 2);
    unsigned short* p1b = (unsigned short*)alloc((size_t)128 * 128 * 2);
    unsigned short* p2a = (unsigned short*)alloc((size_t)128 * 256 * 2);
    unsigned short* p2b = (unsigned short*)alloc((size_t)256 * 128 * 2);
    unsigned short* p3a = (unsigned short*)alloc((size_t)128 * 256 * 2);
    unsigned short* p3b = (unsigned short*)alloc((size_t)256 * 128 * 2);
    int* offs = (int*)alloc((size_t)(N + 1) * 4);
    int* csr  = (int*)alloc((size_t)E * 4);
    unsigned int* staged = (unsigned int*)alloc((size_t)E * 4);
    int* bh   = (int*)alloc((size_t)BH * 4);
    int* bhs  = (int*)alloc((size_t)BH * 4);
    int* part = (int*)alloc(1024);
    int* boff = (int*)alloc(1024);
    int* flag = (int*)alloc(256);

    // ---- CSR build ----
    detect_i64_kernel<<<1, 64, 0, stream>>>((const unsigned int*)ei, flag);
    part_hist_kernel<<<G2, 256, 0, stream>>>(ei, flag, bh, E, NB, PB);
    const int G1 = (BH + 1023) / 1024;   // 196
    scan1_kernel<<<G1, 1024, 0, stream>>>(bh, bhs, part, BH);
    scan2_kernel<<<1, 256, 0, stream>>>(part, boff, G1);
    scan3g_kernel<<<G1, 1024, 0, stream>>>(bhs, boff, BH);
    part_scatter_kernel<<<G2, 256, 0, stream>>>(ei, flag, bhs, staged, E, NB, PB);
    csr_local_kernel<<<NB, 256, 0, stream>>>(staged, bhs, offs, csr, N, E, NB, G2);

    // ---- fused weight packing ----
    {
        PWAll P;
        const PW descs[7] = {
            {Wemb, pWe, 64, 128}, {w1a, p1a, 128, 128}, {w1b, p1b, 128, 128},
            {w2a, p2a, 128, 256}, {w2b, p2b, 256, 128}, {w3a, p3a, 128, 256},
            {w3b, p3b, 256, 128}};
        int c = 0;
        for (int k = 0; k < 7; ++k) {
            P.d[k] = descs[k];
            P.cum[k] = c;
            c += (descs[k].KOUT / 32) * (descs[k].K / 16) * 64;
        }
        P.cum[7] = c;
        packall_kernel<<<(c + 255) / 256, 256, 0, stream>>>(P);
    }

    const int MMB = Mpad / 128;      // 782 tiles
    const int AGB = (N + 15) / 16;   // 16 nodes per block
    const int PGRID = 768;           // persistent blocks: 3/CU x 256 CUs

    // ---- embed: H = x @ W_embed (f32 read directly) ----
    mm_embed<<<MMB, 256, 0, stream>>>(x, pWe, Ha, N);

    // ---- layer 1: 128 -> 128(relu) -> 128 ----
    aggz_kernel<<<AGB, 256, 0, stream>>>(Ha, offs, csr, eps1, Zb, N);
    fused_mlp<128, false, false><<<PGRID, 256, 0, stream>>>(Zb, p1a, b1a, p1b, b1b, Hb2, N, MMB);

    // ---- layer 2: 128 -> 256(relu) -> 128(relu) ----
    aggz_kernel<<<AGB, 256, 0, stream>>>(Hb2, offs, csr, eps2, Zb, N);
    fused_mlp<256, true, false><<<PGRID, 256, 0, stream>>>(Zb, p2a, b2a, p2b, b2b, Ha, N, MMB);

    // ---- layer 3: 128 -> 256(relu) -> 128(relu), f32 out ----
    aggz_kernel<<<AGB, 256, 0, stream>>>(Ha, offs, csr, eps3, Zb, N);
    fused_mlp<256, true, true><<<PGRID, 256, 0, stream>>>(Zb, p3a, b3a, p3b, b3b, d_out, N, MMB);
}

// Round 12
// 503.708 us; speedup vs baseline: 1.4152x; 1.4152x over previous
//
#include <hip/hip_runtime.h>
#include <hip/hip_bf16.h>
#include <stdint.h>

// ---------------------------------------------------------------------------
// GIN forward, round 12: persistent fused MLP with NO min-wave launch bound
// (round 11's (256,3) forced 84 VGPR -> 128-reg accumulator spill -> 338 MB
// scratch traffic). Body identical to round 10 (160 VGPR, no spill); LDS
// allocated once per resident block. aggz / CSR / embed unchanged.
// ---------------------------------------------------------------------------

typedef __attribute__((ext_vector_type(8))) short short8;
typedef __attribute__((ext_vector_type(16))) float float16v;

#define BKT 512       // nodes per bucket (dst >> 9)
#define NBMAX 256     // max buckets held in LDS (NB = 196 here)

__device__ __forceinline__ float b2f_lo(unsigned int u) {
    return __uint_as_float(u << 16);
}
__device__ __forceinline__ float b2f_hi(unsigned int u) {
    return __uint_as_float(u & 0xffff0000u);
}
__device__ __forceinline__ unsigned short f2b(float f) {
    unsigned int u = __float_as_uint(f);
    return (unsigned short)((u + 0x7fffu + ((u >> 16) & 1u)) >> 16);  // RNE
}

// ---------------- edge-index dtype detection ----------------
__global__ void detect_i64_kernel(const unsigned int* ei, int* flag) {
    if (threadIdx.x == 0) {
        int is64 = 1;
        for (int e = 0; e < 64; ++e)
            if (ei[2 * e + 1] != 0u) { is64 = 0; break; }
        *flag = is64;
    }
}

__device__ __forceinline__ int edge_at(const int* ei32, int is64, long long pos) {
    if (is64) return (int)(((const long long*)ei32)[pos]);
    return ei32[pos];
}

// ---------------- radix partition pass 1 ----------------
__global__ __launch_bounds__(256) void part_hist_kernel(
        const int* __restrict__ ei, const int* __restrict__ flag,
        int* __restrict__ bh, int E, int NB, int PB) {
    __shared__ int h[NBMAX];
    const int g = blockIdx.x, tid = threadIdx.x;
    const int is64 = *flag;
    for (int i = tid; i < NB; i += 256) h[i] = 0;
    __syncthreads();
    const int e0 = g * PB, e1 = min(e0 + PB, E);
    for (int e = e0 + tid; e < e1; e += 256) {
        int d = edge_at(ei, is64, (long long)E + e);
        atomicAdd(&h[d >> 9], 1);
    }
    __syncthreads();
    for (int i = tid; i < NB; i += 256) bh[i * gridDim.x + g] = h[i];
}

// ---------------- generic multi-block exclusive scan ----------------
__global__ __launch_bounds__(1024) void scan1_kernel(
        const int* __restrict__ in, int* __restrict__ out,
        int* __restrict__ partial, int n) {
    __shared__ int sm[1024];
    const int t = threadIdx.x;
    const int i = blockIdx.x * 1024 + t;
    int v = (i < n) ? in[i] : 0;
    sm[t] = v;
    __syncthreads();
#pragma unroll
    for (int off = 1; off < 1024; off <<= 1) {
        int x = (t >= off) ? sm[t - off] : 0;
        __syncthreads();
        sm[t] += x;
        __syncthreads();
    }
    if (i < n) out[i] = sm[t] - v;
    if (t == 1023) partial[blockIdx.x] = sm[1023];
}

__global__ __launch_bounds__(256) void scan2_kernel(
        int* __restrict__ partial, int* __restrict__ blockoff, int g1) {
    __shared__ int sm[256];
    const int t = threadIdx.x;
    int v = (t < g1) ? partial[t] : 0;
    sm[t] = v;
    __syncthreads();
#pragma unroll
    for (int off = 1; off < 256; off <<= 1) {
        int x = (t >= off) ? sm[t - off] : 0;
        __syncthreads();
        sm[t] += x;
        __syncthreads();
    }
    blockoff[t] = sm[t] - v;
}

__global__ __launch_bounds__(1024) void scan3g_kernel(
        int* __restrict__ a, const int* __restrict__ blockoff, int n) {
    int i = blockIdx.x * 1024 + threadIdx.x;
    if (i < n) a[i] += blockoff[blockIdx.x];
}

// ---------------- pass 2: scatter into bucket-contiguous staging ----------------
__global__ __launch_bounds__(256) void part_scatter_kernel(
        const int* __restrict__ ei, const int* __restrict__ flag,
        const int* __restrict__ bhs, unsigned int* __restrict__ staged,
        int E, int NB, int PB) {
    __shared__ int cur[NBMAX];
    const int g = blockIdx.x, tid = threadIdx.x;
    const int is64 = *flag;
    for (int i = tid; i < NB; i += 256) cur[i] = bhs[i * gridDim.x + g];
    __syncthreads();
    const int e0 = g * PB, e1 = min(e0 + PB, E);
    for (int e = e0 + tid; e < e1; e += 256) {
        int d = edge_at(ei, is64, (long long)E + e);
        int s = edge_at(ei, is64, (long long)e);
        int b = d >> 9;
        int p = atomicAdd(&cur[b], 1);
        staged[p] = ((unsigned int)(d & (BKT - 1)) << 17) | (unsigned int)s;
    }
}

// ---------------- pass 3: per-bucket counting sort -> offs + csr ----------------
__global__ __launch_bounds__(256) void csr_local_kernel(
        const unsigned int* __restrict__ staged, const int* __restrict__ bhs,
        int* __restrict__ offs, int* __restrict__ csr, int N, int E, int NB, int G2) {
    __shared__ int hist[BKT];
    __shared__ int cur[BKT];
    const int b = blockIdx.x;
    const int tid = threadIdx.x;
    const int start = bhs[b * G2];
    const int end = (b + 1 < NB) ? bhs[(b + 1) * G2] : E;
    const int node0 = b * BKT;
    for (int i = tid; i < BKT; i += 256) hist[i] = 0;
    __syncthreads();
    for (int i = start + tid; i < end; i += 256)
        atomicAdd(&hist[staged[i] >> 17], 1);
    __syncthreads();
    const int i0 = tid * 2, i1 = i0 + 1;
    for (int off = 1; off < BKT; off <<= 1) {
        int v0 = (i0 >= off) ? hist[i0 - off] : 0;
        int v1 = (i1 >= off) ? hist[i1 - off] : 0;
        __syncthreads();
        hist[i0] += v0;
        hist[i1] += v1;
        __syncthreads();
    }
    for (int i = tid; i < BKT; i += 256) {
        int node = node0 + i;
        if (node < N) {
            int e0 = start + ((i == 0) ? 0 : hist[i - 1]);
            offs[node] = e0;
            cur[i] = e0;
        }
    }
    if (b == NB - 1 && tid == 0) offs[N] = E;
    __syncthreads();
    for (int i = start + tid; i < end; i += 256) {
        unsigned int v = staged[i];
        int dl = v >> 17;
        int src = (int)(v & 0x1ffff);
        int p = atomicAdd(&cur[dl], 1);
        csr[p] = src;
    }
}

// ---------------- fused weight pack (32x32x16 B-fragments), 7 weights ----------------
struct PW { const float* W; unsigned short* o; int K; int KOUT; };
struct PWAll { PW d[7]; int cum[8]; };

__global__ __launch_bounds__(256) void packall_kernel(PWAll P) {
    int id = blockIdx.x * blockDim.x + threadIdx.x;
    if (id >= P.cum[7]) return;
    int w = 0;
#pragma unroll
    for (int k = 1; k < 7; ++k) w += (id >= P.cum[k]);
    const int local = id - P.cum[w];
    const float* W = P.d[w].W;
    unsigned short* out = P.d[w].o;
    const int K = P.d[w].K, KOUT = P.d[w].KOUT;
    const int KS = K / 16;
    const int l = local & 63;
    const int s = (local >> 6) % KS;
    const int T = local / (KS * 64);
    const int kbase = s * 16 + ((l >> 5) << 3);
    const int n = T * 32 + (l & 31);
#pragma unroll
    for (int j = 0; j < 8; ++j)
        out[(long long)local * 8 + j] = f2b(W[(long long)(kbase + j) * KOUT + n]);
}

// ---------------- embed: H = x(f32) @ W_embed ----------------
__global__ __launch_bounds__(256) void mm_embed(
        const float* __restrict__ X, const unsigned short* __restrict__ Wp,
        unsigned short* __restrict__ out, int Mreal) {
    constexpr int KS = 4;
    const int tid = threadIdx.x;
    const int w = tid >> 6;
    const int l = tid & 63;
    const int lm = l & 31;
    const int lk = l >> 5;
    const int wr = w & 1, wc = w >> 1;
    const long long R0 = (long long)blockIdx.x * 128 + wr * 64;
    const int T0 = (wc * 64) >> 5;

    const long long r0 = (R0 + lm < Mreal) ? (R0 + lm) : (Mreal - 1);
    const long long r1 = (R0 + 32 + lm < Mreal) ? (R0 + 32 + lm) : (Mreal - 1);
    const float* xr0 = X + r0 * 64 + lk * 8;
    const float* xr1 = X + r1 * 64 + lk * 8;
    const unsigned short* bb0 = Wp + ((long long)T0 * KS * 64 + l) * 8;
    const unsigned short* bb1 = Wp + ((long long)(T0 + 1) * KS * 64 + l) * 8;

    float16v acc00 = {}, acc01 = {}, acc10 = {}, acc11 = {};
#pragma unroll
    for (int s = 0; s < KS; ++s) {
        float4 f0a = *(const float4*)(xr0 + s * 16);
        float4 f0b = *(const float4*)(xr0 + s * 16 + 4);
        float4 f1a = *(const float4*)(xr1 + s * 16);
        float4 f1b = *(const float4*)(xr1 + s * 16 + 4);
        short8 a0, a1;
        a0[0] = (short)f2b(f0a.x); a0[1] = (short)f2b(f0a.y);
        a0[2] = (short)f2b(f0a.z); a0[3] = (short)f2b(f0a.w);
        a0[4] = (short)f2b(f0b.x); a0[5] = (short)f2b(f0b.y);
        a0[6] = (short)f2b(f0b.z); a0[7] = (short)f2b(f0b.w);
        a1[0] = (short)f2b(f1a.x); a1[1] = (short)f2b(f1a.y);
        a1[2] = (short)f2b(f1a.z); a1[3] = (short)f2b(f1a.w);
        a1[4] = (short)f2b(f1b.x); a1[5] = (short)f2b(f1b.y);
        a1[6] = (short)f2b(f1b.z); a1[7] = (short)f2b(f1b.w);
        short8 b0 = *(const short8*)(bb0 + (long long)s * 64 * 8);
        short8 b1 = *(const short8*)(bb1 + (long long)s * 64 * 8);
        acc00 = __builtin_amdgcn_mfma_f32_32x32x16_bf16(a0, b0, acc00, 0, 0, 0);
        acc01 = __builtin_amdgcn_mfma_f32_32x32x16_bf16(a0, b1, acc01, 0, 0, 0);
        acc10 = __builtin_amdgcn_mfma_f32_32x32x16_bf16(a1, b0, acc10, 0, 0, 0);
        acc11 = __builtin_amdgcn_mfma_f32_32x32x16_bf16(a1, b1, acc11, 0, 0, 0);
    }
    auto st = [&](float16v acc, long long rb, int col) {
#pragma unroll
        for (int r = 0; r < 16; ++r) {
            long long row = rb + (r & 3) + 8 * (r >> 2);
            out[row * 128 + col] = f2b(acc[r]);
        }
    };
    const long long rbase = R0 + 4 * lk;
    st(acc00, rbase,      wc * 64 + lm);
    st(acc01, rbase,      wc * 64 + 32 + lm);
    st(acc10, rbase + 32, wc * 64 + lm);
    st(acc11, rbase + 32, wc * 64 + 32 + lm);
}

// ---------------- aggregation (standalone, high occupancy) ----------------
__global__ __launch_bounds__(256) void aggz_kernel(
        const unsigned short* __restrict__ H, const int* __restrict__ offs,
        const int* __restrict__ csr, const float* __restrict__ eps,
        unsigned short* __restrict__ Z, int n) {
    const int node = blockIdx.x * 16 + (threadIdx.x >> 4);
    const int c8 = (threadIdx.x & 15) << 3;
    if (node >= n) return;
    const int beg = offs[node];
    const int end = offs[node + 1];
    float a0 = 0.f, a1 = 0.f, a2 = 0.f, a3 = 0.f;
    float a4 = 0.f, a5 = 0.f, a6 = 0.f, a7 = 0.f;
    int i = beg;
    for (; i + 3 < end; i += 4) {
        const int j0 = csr[i], j1 = csr[i + 1], j2 = csr[i + 2], j3 = csr[i + 3];
        const uint4 u0 = *(const uint4*)(H + ((long long)j0 << 7) + c8);
        const uint4 u1 = *(const uint4*)(H + ((long long)j1 << 7) + c8);
        const uint4 u2 = *(const uint4*)(H + ((long long)j2 << 7) + c8);
        const uint4 u3 = *(const uint4*)(H + ((long long)j3 << 7) + c8);
        a0 += (b2f_lo(u0.x) + b2f_lo(u1.x)) + (b2f_lo(u2.x) + b2f_lo(u3.x));
        a1 += (b2f_hi(u0.x) + b2f_hi(u1.x)) + (b2f_hi(u2.x) + b2f_hi(u3.x));
        a2 += (b2f_lo(u0.y) + b2f_lo(u1.y)) + (b2f_lo(u2.y) + b2f_lo(u3.y));
        a3 += (b2f_hi(u0.y) + b2f_hi(u1.y)) + (b2f_hi(u2.y) + b2f_hi(u3.y));
        a4 += (b2f_lo(u0.z) + b2f_lo(u1.z)) + (b2f_lo(u2.z) + b2f_lo(u3.z));
        a5 += (b2f_hi(u0.z) + b2f_hi(u1.z)) + (b2f_hi(u2.z) + b2f_hi(u3.z));
        a6 += (b2f_lo(u0.w) + b2f_lo(u1.w)) + (b2f_lo(u2.w) + b2f_lo(u3.w));
        a7 += (b2f_hi(u0.w) + b2f_hi(u1.w)) + (b2f_hi(u2.w) + b2f_hi(u3.w));
    }
    for (; i < end; ++i) {
        const uint4 u0 = *(const uint4*)(H + ((long long)csr[i] << 7) + c8);
        a0 += b2f_lo(u0.x); a1 += b2f_hi(u0.x);
        a2 += b2f_lo(u0.y); a3 += b2f_hi(u0.y);
        a4 += b2f_lo(u0.z); a5 += b2f_hi(u0.z);
        a6 += b2f_lo(u0.w); a7 += b2f_hi(u0.w);
    }
    const uint4 uh = *(const uint4*)(H + ((long long)node << 7) + c8);
    const float e = 1.0f + eps[0];
    a0 = fmaf(e, b2f_lo(uh.x), a0); a1 = fmaf(e, b2f_hi(uh.x), a1);
    a2 = fmaf(e, b2f_lo(uh.y), a2); a3 = fmaf(e, b2f_hi(uh.y), a3);
    a4 = fmaf(e, b2f_lo(uh.z), a4); a5 = fmaf(e, b2f_hi(uh.z), a5);
    a6 = fmaf(e, b2f_lo(uh.w), a6); a7 = fmaf(e, b2f_hi(uh.w), a7);
    uint4 o;
    o.x = ((unsigned int)f2b(a1) << 16) | (unsigned int)f2b(a0);
    o.y = ((unsigned int)f2b(a3) << 16) | (unsigned int)f2b(a2);
    o.z = ((unsigned int)f2b(a5) << 16) | (unsigned int)f2b(a4);
    o.w = ((unsigned int)f2b(a7) << 16) | (unsigned int)f2b(a6);
    *(uint4*)(Z + ((long long)node << 7) + c8) = o;
}

// ---------------- PERSISTENT fused MLP (no min-wave bound) ----------------
// Grid = 768 blocks; residency set naturally by 160 VGPR (3 waves/SIMD ->
// 3 blocks/CU). Each block grid-strides over M-tiles; LDS (32 KB T tile)
// allocated once per resident block.
template<int KMID, bool RELU2, bool OUTF32>
__global__ __launch_bounds__(256) void fused_mlp(
        const unsigned short* __restrict__ Zin,
        const unsigned short* __restrict__ Wap, const float* __restrict__ ba,
        const unsigned short* __restrict__ Wbp, const float* __restrict__ bb,
        void* __restrict__ outp, int Mreal, int ntiles) {
    __shared__ unsigned short lds[16384];   // 32 KB: T tile, 2048 slots x 16 B
    const int tid = threadIdx.x;
    const int w = tid >> 6;
    const int l = tid & 63;
    const int lm = l & 31;
    const int lk = l >> 5;
    const int wr = w & 1, wc = w >> 1;
    constexpr int KS1 = 8;            // KIN = 128
    constexpr int KSB = KMID / 16;    // Wb K-steps (total)
    constexpr int NH = KMID / 128;    // halves

    for (int tile = blockIdx.x; tile < ntiles; tile += gridDim.x) {
        const long long R0 = (long long)tile * 128;
        const unsigned short* arow0 = Zin + (R0 + wr * 64 + lm) * 128 + lk * 8;
        const unsigned short* arow1 = arow0 + 32 * 128;

        float16v d00 = {}, d01 = {}, d10 = {}, d11 = {};

        for (int h = 0; h < NH; ++h) {
            __syncthreads();   // LDS reuse guard (prev half / prev tile reads done)

            // stage 1: Z @ Wa (cols h*128 + wc*64 .. +64), bias+relu -> T in LDS
            {
                float16v c00 = {}, c01 = {}, c10 = {}, c11 = {};
                const int T1 = (wc * 64 + h * 128) >> 5;
                const unsigned short* bp0 = Wap + ((long long)T1 * KS1 * 64 + l) * 8;
                const unsigned short* bp1 = Wap + ((long long)(T1 + 1) * KS1 * 64 + l) * 8;
#pragma unroll
                for (int s = 0; s < KS1; ++s) {
                    short8 a0 = *(const short8*)(arow0 + s * 16);
                    short8 a1 = *(const short8*)(arow1 + s * 16);
                    short8 b0 = *(const short8*)(bp0 + (long long)s * 64 * 8);
                    short8 b1 = *(const short8*)(bp1 + (long long)s * 64 * 8);
                    c00 = __builtin_amdgcn_mfma_f32_32x32x16_bf16(a0, b0, c00, 0, 0, 0);
                    c01 = __builtin_amdgcn_mfma_f32_32x32x16_bf16(a0, b1, c01, 0, 0, 0);
                    c10 = __builtin_amdgcn_mfma_f32_32x32x16_bf16(a1, b0, c10, 0, 0, 0);
                    c11 = __builtin_amdgcn_mfma_f32_32x32x16_bf16(a1, b1, c11, 0, 0, 0);
                }
                auto wT = [&](float16v acc, int rbase, int cl) {
                    const float bv = ba[h * 128 + cl];
                    const int secT = cl >> 3;
                    const int cj = cl & 7;
#pragma unroll
                    for (int r = 0; r < 16; ++r) {
                        float v = fmaxf(acc[r] + bv, 0.f);
                        const int row = rbase + (r & 3) + 8 * (r >> 2);
                        lds[(secT * 128 + (row ^ (secT & 7))) * 8 + cj] = f2b(v);
                    }
                };
                wT(c00, wr * 64 + 4 * lk,      wc * 64 + lm);
                wT(c01, wr * 64 + 4 * lk,      wc * 64 + 32 + lm);
                wT(c10, wr * 64 + 32 + 4 * lk, wc * 64 + lm);
                wT(c11, wr * 64 + 32 + 4 * lk, wc * 64 + 32 + lm);
            }
            __syncthreads();

            // stage 2: T @ Wb (k = h*128 .. +128), accumulate
            {
                const int T2 = (wc * 64) >> 5;
                const unsigned short* bp0 = Wbp + ((long long)T2 * KSB * 64 + l) * 8;
                const unsigned short* bp1 = Wbp + ((long long)(T2 + 1) * KSB * 64 + l) * 8;
#pragma unroll
                for (int s = 0; s < 8; ++s) {
                    const int sec = s * 2 + lk;
                    short8 a0 = *(const short8*)&lds[(sec * 128 + ((wr * 64 + lm) ^ (sec & 7))) * 8];
                    short8 a1 = *(const short8*)&lds[(sec * 128 + ((wr * 64 + 32 + lm) ^ (sec & 7))) * 8];
                    short8 b0 = *(const short8*)(bp0 + (long long)(h * 8 + s) * 64 * 8);
                    short8 b1 = *(const short8*)(bp1 + (long long)(h * 8 + s) * 64 * 8);
                    d00 = __builtin_amdgcn_mfma_f32_32x32x16_bf16(a0, b0, d00, 0, 0, 0);
                    d01 = __builtin_amdgcn_mfma_f32_32x32x16_bf16(a0, b1, d01, 0, 0, 0);
                    d10 = __builtin_amdgcn_mfma_f32_32x32x16_bf16(a1, b0, d10, 0, 0, 0);
                    d11 = __builtin_amdgcn_mfma_f32_32x32x16_bf16(a1, b1, d11, 0, 0, 0);
                }
            }
        }

        auto st = [&](float16v acc, int rbase, int col) {
            const float bv = bb[col];
#pragma unroll
            for (int r = 0; r < 16; ++r) {
                float v = acc[r] + bv;
                if (RELU2) v = fmaxf(v, 0.f);
                const long long row = R0 + rbase + (r & 3) + 8 * (r >> 2);
                if (OUTF32) {
                    if (row < Mreal) ((float*)outp)[row * 128 + col] = v;
                } else {
                    ((unsigned short*)outp)[row * 128 + col] = f2b(v);
                }
            }
        };
        st(d00, wr * 64 + 4 * lk,      wc * 64 + lm);
        st(d01, wr * 64 + 4 * lk,      wc * 64 + 32 + lm);
        st(d10, wr * 64 + 32 + 4 * lk, wc * 64 + lm);
        st(d11, wr * 64 + 32 + 4 * lk, wc * 64 + 32 + lm);
    }
}

extern "C" void kernel_launch(void* const* d_in, const int* in_sizes, int n_in,
                              void* d_out, int out_size, void* d_ws, size_t ws_size,
                              hipStream_t stream) {
    const float* x    = (const float*)d_in[0];
    const int*   ei   = (const int*)d_in[1];
    const float* Wemb = (const float*)d_in[2];
    const float* eps1 = (const float*)d_in[3];
    const float* w1a  = (const float*)d_in[4];
    const float* b1a  = (const float*)d_in[5];
    const float* w1b  = (const float*)d_in[6];
    const float* b1b  = (const float*)d_in[7];
    const float* eps2 = (const float*)d_in[8];
    const float* w2a  = (const float*)d_in[9];
    const float* b2a  = (const float*)d_in[10];
    const float* w2b  = (const float*)d_in[11];
    const float* b2b  = (const float*)d_in[12];
    const float* eps3 = (const float*)d_in[13];
    const float* w3a  = (const float*)d_in[14];
    const float* b3a  = (const float*)d_in[15];
    const float* w3b  = (const float*)d_in[16];
    const float* b3b  = (const float*)d_in[17];

    const int N = in_sizes[0] / 64;   // 100000
    const int E = in_sizes[1] / 2;    // 1600000
    const int Mpad = ((N + 127) / 128) * 128;  // 100096
    const int NB = (N + BKT - 1) / BKT;   // 196
    const int G2 = 1024;
    const int PB = (E + G2 - 1) / G2;
    const int BH = NB * G2;

    char* ws = (char*)d_ws;
    size_t off = 0;
    auto alloc = [&](size_t bytes) -> void* {
        void* p = ws + off;
        off = (off + bytes + 255) & ~(size_t)255;
        return p;
    };
    unsigned short* Ha  = (unsigned short*)alloc((size_t)Mpad * 128 * 2);
    unsigned short* Hb2 = (unsigned short*)alloc((size_t)Mpad * 128 * 2);
    unsigned short* Zb  = (unsigned short*)alloc((size_t)Mpad * 128 * 2);
    unsigned short* pWe = (unsigned short*)alloc((size_t)64 * 128 * 2);
    unsigned short* p1a = (unsigned short*)alloc((size_t)128 * 128 * 2);
    unsigned short* p1b = (unsigned short*)alloc((size_t)128 * 128 * 2);
    unsigned short* p2a = (unsigned short*)alloc((size_t)128 * 256 * 2);
    unsigned short* p2b = (unsigned short*)alloc((size_t)256 * 128 * 2);
    unsigned short* p3a = (unsigned short*)alloc((size_t)128 * 256 * 2);
    unsigned short* p3b = (unsigned short*)alloc((size_t)256 * 128 * 2);
    int* offs = (int*)alloc((size_t)(N + 1) * 4);
    int* csr  = (int*)alloc((size_t)E * 4);
    unsigned int* staged = (unsigned int*)alloc((size_t)E * 4);
    int* bh   = (int*)alloc((size_t)BH * 4);
    int* bhs  = (int*)alloc((size_t)BH * 4);
    int* part = (int*)alloc(1024);
    int* boff = (int*)alloc(1024);
    int* flag = (int*)alloc(256);

    // ---- CSR build ----
    detect_i64_kernel<<<1, 64, 0, stream>>>((const unsigned int*)ei, flag);
    part_hist_kernel<<<G2, 256, 0, stream>>>(ei, flag, bh, E, NB, PB);
    const int G1 = (BH + 1023) / 1024;   // 196
    scan1_kernel<<<G1, 1024, 0, stream>>>(bh, bhs, part, BH);
    scan2_kernel<<<1, 256, 0, stream>>>(part, boff, G1);
    scan3g_kernel<<<G1, 1024, 0, stream>>>(bhs, boff, BH);
    part_scatter_kernel<<<G2, 256, 0, stream>>>(ei, flag, bhs, staged, E, NB, PB);
    csr_local_kernel<<<NB, 256, 0, stream>>>(staged, bhs, offs, csr, N, E, NB, G2);

    // ---- fused weight packing ----
    {
        PWAll P;
        const PW descs[7] = {
            {Wemb, pWe, 64, 128}, {w1a, p1a, 128, 128}, {w1b, p1b, 128, 128},
            {w2a, p2a, 128, 256}, {w2b, p2b, 256, 128}, {w3a, p3a, 128, 256},
            {w3b, p3b, 256, 128}};
        int c = 0;
        for (int k = 0; k < 7; ++k) {
            P.d[k] = descs[k];
            P.cum[k] = c;
            c += (descs[k].KOUT / 32) * (descs[k].K / 16) * 64;
        }
        P.cum[7] = c;
        packall_kernel<<<(c + 255) / 256, 256, 0, stream>>>(P);
    }

    const int MMB = Mpad / 128;      // 782 tiles
    const int AGB = (N + 15) / 16;   // 16 nodes per block
    const int PGRID = 768;           // 3 blocks/CU x 256 CUs (VGPR-natural)

    // ---- embed: H = x @ W_embed (f32 read directly) ----
    mm_embed<<<MMB, 256, 0, stream>>>(x, pWe, Ha, N);

    // ---- layer 1: 128 -> 128(relu) -> 128 ----
    aggz_kernel<<<AGB, 256, 0, stream>>>(Ha, offs, csr, eps1, Zb, N);
    fused_mlp<128, false, false><<<PGRID, 256, 0, stream>>>(Zb, p1a, b1a, p1b, b1b, Hb2, N, MMB);

    // ---- layer 2: 128 -> 256(relu) -> 128(relu) ----
    aggz_kernel<<<AGB, 256, 0, stream>>>(Hb2, offs, csr, eps2, Zb, N);
    fused_mlp<256, true, false><<<PGRID, 256, 0, stream>>>(Zb, p2a, b2a, p2b, b2b, Ha, N, MMB);

    // ---- layer 3: 128 -> 256(relu) -> 128(relu), f32 out ----
    aggz_kernel<<<AGB, 256, 0, stream>>>(Ha, offs, csr, eps3, Zb, N);
    fused_mlp<256, true, true><<<PGRID, 256, 0, stream>>>(Zb, p3a, b3a, p3b, b3b, d_out, N, MMB);
}

// Round 13
// 494.386 us; speedup vs baseline: 1.4419x; 1.0189x over previous
//
#include <hip/hip_runtime.h>
#include <hip/hip_bf16.h>
#include <stdint.h>

// ---------------------------------------------------------------------------
// GIN forward, round 13: fused MLP re-tiled for occupancy — 512-thread blocks,
// 8 waves of 64x32 output each (accumulators 64 regs instead of 128 ->
// target <=128 VGPR -> 4 waves/SIMD). T in LDS (32 KB, XOR swizzle).
// aggz / CSR / embed unchanged from round 12.
// ---------------------------------------------------------------------------

typedef __attribute__((ext_vector_type(8))) short short8;
typedef __attribute__((ext_vector_type(16))) float float16v;

#define BKT 512       // nodes per bucket (dst >> 9)
#define NBMAX 256     // max buckets held in LDS (NB = 196 here)

__device__ __forceinline__ float b2f_lo(unsigned int u) {
    return __uint_as_float(u << 16);
}
__device__ __forceinline__ float b2f_hi(unsigned int u) {
    return __uint_as_float(u & 0xffff0000u);
}
__device__ __forceinline__ unsigned short f2b(float f) {
    unsigned int u = __float_as_uint(f);
    return (unsigned short)((u + 0x7fffu + ((u >> 16) & 1u)) >> 16);  // RNE
}

// ---------------- edge-index dtype detection ----------------
__global__ void detect_i64_kernel(const unsigned int* ei, int* flag) {
    if (threadIdx.x == 0) {
        int is64 = 1;
        for (int e = 0; e < 64; ++e)
            if (ei[2 * e + 1] != 0u) { is64 = 0; break; }
        *flag = is64;
    }
}

__device__ __forceinline__ int edge_at(const int* ei32, int is64, long long pos) {
    if (is64) return (int)(((const long long*)ei32)[pos]);
    return ei32[pos];
}

// ---------------- radix partition pass 1 ----------------
__global__ __launch_bounds__(256) void part_hist_kernel(
        const int* __restrict__ ei, const int* __restrict__ flag,
        int* __restrict__ bh, int E, int NB, int PB) {
    __shared__ int h[NBMAX];
    const int g = blockIdx.x, tid = threadIdx.x;
    const int is64 = *flag;
    for (int i = tid; i < NB; i += 256) h[i] = 0;
    __syncthreads();
    const int e0 = g * PB, e1 = min(e0 + PB, E);
    for (int e = e0 + tid; e < e1; e += 256) {
        int d = edge_at(ei, is64, (long long)E + e);
        atomicAdd(&h[d >> 9], 1);
    }
    __syncthreads();
    for (int i = tid; i < NB; i += 256) bh[i * gridDim.x + g] = h[i];
}

// ---------------- generic multi-block exclusive scan ----------------
__global__ __launch_bounds__(1024) void scan1_kernel(
        const int* __restrict__ in, int* __restrict__ out,
        int* __restrict__ partial, int n) {
    __shared__ int sm[1024];
    const int t = threadIdx.x;
    const int i = blockIdx.x * 1024 + t;
    int v = (i < n) ? in[i] : 0;
    sm[t] = v;
    __syncthreads();
#pragma unroll
    for (int off = 1; off < 1024; off <<= 1) {
        int x = (t >= off) ? sm[t - off] : 0;
        __syncthreads();
        sm[t] += x;
        __syncthreads();
    }
    if (i < n) out[i] = sm[t] - v;
    if (t == 1023) partial[blockIdx.x] = sm[1023];
}

__global__ __launch_bounds__(256) void scan2_kernel(
        int* __restrict__ partial, int* __restrict__ blockoff, int g1) {
    __shared__ int sm[256];
    const int t = threadIdx.x;
    int v = (t < g1) ? partial[t] : 0;
    sm[t] = v;
    __syncthreads();
#pragma unroll
    for (int off = 1; off < 256; off <<= 1) {
        int x = (t >= off) ? sm[t - off] : 0;
        __syncthreads();
        sm[t] += x;
        __syncthreads();
    }
    blockoff[t] = sm[t] - v;
}

__global__ __launch_bounds__(1024) void scan3g_kernel(
        int* __restrict__ a, const int* __restrict__ blockoff, int n) {
    int i = blockIdx.x * 1024 + threadIdx.x;
    if (i < n) a[i] += blockoff[blockIdx.x];
}

// ---------------- pass 2: scatter into bucket-contiguous staging ----------------
__global__ __launch_bounds__(256) void part_scatter_kernel(
        const int* __restrict__ ei, const int* __restrict__ flag,
        const int* __restrict__ bhs, unsigned int* __restrict__ staged,
        int E, int NB, int PB) {
    __shared__ int cur[NBMAX];
    const int g = blockIdx.x, tid = threadIdx.x;
    const int is64 = *flag;
    for (int i = tid; i < NB; i += 256) cur[i] = bhs[i * gridDim.x + g];
    __syncthreads();
    const int e0 = g * PB, e1 = min(e0 + PB, E);
    for (int e = e0 + tid; e < e1; e += 256) {
        int d = edge_at(ei, is64, (long long)E + e);
        int s = edge_at(ei, is64, (long long)e);
        int b = d >> 9;
        int p = atomicAdd(&cur[b], 1);
        staged[p] = ((unsigned int)(d & (BKT - 1)) << 17) | (unsigned int)s;
    }
}

// ---------------- pass 3: per-bucket counting sort -> offs + csr ----------------
__global__ __launch_bounds__(256) void csr_local_kernel(
        const unsigned int* __restrict__ staged, const int* __restrict__ bhs,
        int* __restrict__ offs, int* __restrict__ csr, int N, int E, int NB, int G2) {
    __shared__ int hist[BKT];
    __shared__ int cur[BKT];
    const int b = blockIdx.x;
    const int tid = threadIdx.x;
    const int start = bhs[b * G2];
    const int end = (b + 1 < NB) ? bhs[(b + 1) * G2] : E;
    const int node0 = b * BKT;
    for (int i = tid; i < BKT; i += 256) hist[i] = 0;
    __syncthreads();
    for (int i = start + tid; i < end; i += 256)
        atomicAdd(&hist[staged[i] >> 17], 1);
    __syncthreads();
    const int i0 = tid * 2, i1 = i0 + 1;
    for (int off = 1; off < BKT; off <<= 1) {
        int v0 = (i0 >= off) ? hist[i0 - off] : 0;
        int v1 = (i1 >= off) ? hist[i1 - off] : 0;
        __syncthreads();
        hist[i0] += v0;
        hist[i1] += v1;
        __syncthreads();
    }
    for (int i = tid; i < BKT; i += 256) {
        int node = node0 + i;
        if (node < N) {
            int e0 = start + ((i == 0) ? 0 : hist[i - 1]);
            offs[node] = e0;
            cur[i] = e0;
        }
    }
    if (b == NB - 1 && tid == 0) offs[N] = E;
    __syncthreads();
    for (int i = start + tid; i < end; i += 256) {
        unsigned int v = staged[i];
        int dl = v >> 17;
        int src = (int)(v & 0x1ffff);
        int p = atomicAdd(&cur[dl], 1);
        csr[p] = src;
    }
}

// ---------------- fused weight pack (32x32x16 B-fragments), 7 weights ----------------
struct PW { const float* W; unsigned short* o; int K; int KOUT; };
struct PWAll { PW d[7]; int cum[8]; };

__global__ __launch_bounds__(256) void packall_kernel(PWAll P) {
    int id = blockIdx.x * blockDim.x + threadIdx.x;
    if (id >= P.cum[7]) return;
    int w = 0;
#pragma unroll
    for (int k = 1; k < 7; ++k) w += (id >= P.cum[k]);
    const int local = id - P.cum[w];
    const float* W = P.d[w].W;
    unsigned short* out = P.d[w].o;
    const int K = P.d[w].K, KOUT = P.d[w].KOUT;
    const int KS = K / 16;
    const int l = local & 63;
    const int s = (local >> 6) % KS;
    const int T = local / (KS * 64);
    const int kbase = s * 16 + ((l >> 5) << 3);
    const int n = T * 32 + (l & 31);
#pragma unroll
    for (int j = 0; j < 8; ++j)
        out[(long long)local * 8 + j] = f2b(W[(long long)(kbase + j) * KOUT + n]);
}

// ---------------- embed: H = x(f32) @ W_embed ----------------
__global__ __launch_bounds__(256) void mm_embed(
        const float* __restrict__ X, const unsigned short* __restrict__ Wp,
        unsigned short* __restrict__ out, int Mreal) {
    constexpr int KS = 4;
    const int tid = threadIdx.x;
    const int w = tid >> 6;
    const int l = tid & 63;
    const int lm = l & 31;
    const int lk = l >> 5;
    const int wr = w & 1, wc = w >> 1;
    const long long R0 = (long long)blockIdx.x * 128 + wr * 64;
    const int T0 = (wc * 64) >> 5;

    const long long r0 = (R0 + lm < Mreal) ? (R0 + lm) : (Mreal - 1);
    const long long r1 = (R0 + 32 + lm < Mreal) ? (R0 + 32 + lm) : (Mreal - 1);
    const float* xr0 = X + r0 * 64 + lk * 8;
    const float* xr1 = X + r1 * 64 + lk * 8;
    const unsigned short* bb0 = Wp + ((long long)T0 * KS * 64 + l) * 8;
    const unsigned short* bb1 = Wp + ((long long)(T0 + 1) * KS * 64 + l) * 8;

    float16v acc00 = {}, acc01 = {}, acc10 = {}, acc11 = {};
#pragma unroll
    for (int s = 0; s < KS; ++s) {
        float4 f0a = *(const float4*)(xr0 + s * 16);
        float4 f0b = *(const float4*)(xr0 + s * 16 + 4);
        float4 f1a = *(const float4*)(xr1 + s * 16);
        float4 f1b = *(const float4*)(xr1 + s * 16 + 4);
        short8 a0, a1;
        a0[0] = (short)f2b(f0a.x); a0[1] = (short)f2b(f0a.y);
        a0[2] = (short)f2b(f0a.z); a0[3] = (short)f2b(f0a.w);
        a0[4] = (short)f2b(f0b.x); a0[5] = (short)f2b(f0b.y);
        a0[6] = (short)f2b(f0b.z); a0[7] = (short)f2b(f0b.w);
        a1[0] = (short)f2b(f1a.x); a1[1] = (short)f2b(f1a.y);
        a1[2] = (short)f2b(f1a.z); a1[3] = (short)f2b(f1a.w);
        a1[4] = (short)f2b(f1b.x); a1[5] = (short)f2b(f1b.y);
        a1[6] = (short)f2b(f1b.z); a1[7] = (short)f2b(f1b.w);
        short8 b0 = *(const short8*)(bb0 + (long long)s * 64 * 8);
        short8 b1 = *(const short8*)(bb1 + (long long)s * 64 * 8);
        acc00 = __builtin_amdgcn_mfma_f32_32x32x16_bf16(a0, b0, acc00, 0, 0, 0);
        acc01 = __builtin_amdgcn_mfma_f32_32x32x16_bf16(a0, b1, acc01, 0, 0, 0);
        acc10 = __builtin_amdgcn_mfma_f32_32x32x16_bf16(a1, b0, acc10, 0, 0, 0);
        acc11 = __builtin_amdgcn_mfma_f32_32x32x16_bf16(a1, b1, acc11, 0, 0, 0);
    }
    auto st = [&](float16v acc, long long rb, int col) {
#pragma unroll
        for (int r = 0; r < 16; ++r) {
            long long row = rb + (r & 3) + 8 * (r >> 2);
            out[row * 128 + col] = f2b(acc[r]);
        }
    };
    const long long rbase = R0 + 4 * lk;
    st(acc00, rbase,      wc * 64 + lm);
    st(acc01, rbase,      wc * 64 + 32 + lm);
    st(acc10, rbase + 32, wc * 64 + lm);
    st(acc11, rbase + 32, wc * 64 + 32 + lm);
}

// ---------------- aggregation (standalone, high occupancy) ----------------
__global__ __launch_bounds__(256) void aggz_kernel(
        const unsigned short* __restrict__ H, const int* __restrict__ offs,
        const int* __restrict__ csr, const float* __restrict__ eps,
        unsigned short* __restrict__ Z, int n) {
    const int node = blockIdx.x * 16 + (threadIdx.x >> 4);
    const int c8 = (threadIdx.x & 15) << 3;
    if (node >= n) return;
    const int beg = offs[node];
    const int end = offs[node + 1];
    float a0 = 0.f, a1 = 0.f, a2 = 0.f, a3 = 0.f;
    float a4 = 0.f, a5 = 0.f, a6 = 0.f, a7 = 0.f;
    int i = beg;
    for (; i + 3 < end; i += 4) {
        const int j0 = csr[i], j1 = csr[i + 1], j2 = csr[i + 2], j3 = csr[i + 3];
        const uint4 u0 = *(const uint4*)(H + ((long long)j0 << 7) + c8);
        const uint4 u1 = *(const uint4*)(H + ((long long)j1 << 7) + c8);
        const uint4 u2 = *(const uint4*)(H + ((long long)j2 << 7) + c8);
        const uint4 u3 = *(const uint4*)(H + ((long long)j3 << 7) + c8);
        a0 += (b2f_lo(u0.x) + b2f_lo(u1.x)) + (b2f_lo(u2.x) + b2f_lo(u3.x));
        a1 += (b2f_hi(u0.x) + b2f_hi(u1.x)) + (b2f_hi(u2.x) + b2f_hi(u3.x));
        a2 += (b2f_lo(u0.y) + b2f_lo(u1.y)) + (b2f_lo(u2.y) + b2f_lo(u3.y));
        a3 += (b2f_hi(u0.y) + b2f_hi(u1.y)) + (b2f_hi(u2.y) + b2f_hi(u3.y));
        a4 += (b2f_lo(u0.z) + b2f_lo(u1.z)) + (b2f_lo(u2.z) + b2f_lo(u3.z));
        a5 += (b2f_hi(u0.z) + b2f_hi(u1.z)) + (b2f_hi(u2.z) + b2f_hi(u3.z));
        a6 += (b2f_lo(u0.w) + b2f_lo(u1.w)) + (b2f_lo(u2.w) + b2f_lo(u3.w));
        a7 += (b2f_hi(u0.w) + b2f_hi(u1.w)) + (b2f_hi(u2.w) + b2f_hi(u3.w));
    }
    for (; i < end; ++i) {
        const uint4 u0 = *(const uint4*)(H + ((long long)csr[i] << 7) + c8);
        a0 += b2f_lo(u0.x); a1 += b2f_hi(u0.x);
        a2 += b2f_lo(u0.y); a3 += b2f_hi(u0.y);
        a4 += b2f_lo(u0.z); a5 += b2f_hi(u0.z);
        a6 += b2f_lo(u0.w); a7 += b2f_hi(u0.w);
    }
    const uint4 uh = *(const uint4*)(H + ((long long)node << 7) + c8);
    const float e = 1.0f + eps[0];
    a0 = fmaf(e, b2f_lo(uh.x), a0); a1 = fmaf(e, b2f_hi(uh.x), a1);
    a2 = fmaf(e, b2f_lo(uh.y), a2); a3 = fmaf(e, b2f_hi(uh.y), a3);
    a4 = fmaf(e, b2f_lo(uh.z), a4); a5 = fmaf(e, b2f_hi(uh.z), a5);
    a6 = fmaf(e, b2f_lo(uh.w), a6); a7 = fmaf(e, b2f_hi(uh.w), a7);
    uint4 o;
    o.x = ((unsigned int)f2b(a1) << 16) | (unsigned int)f2b(a0);
    o.y = ((unsigned int)f2b(a3) << 16) | (unsigned int)f2b(a2);
    o.z = ((unsigned int)f2b(a5) << 16) | (unsigned int)f2b(a4);
    o.w = ((unsigned int)f2b(a7) << 16) | (unsigned int)f2b(a6);
    *(uint4*)(Z + ((long long)node << 7) + c8) = o;
}

// ---------------- PERSISTENT fused MLP, 512 threads, 64x32 wave tiles ----------------
// Block = 8 waves; wave (wr,wc) computes rows [wr*64,+64) x cols [wc*32,+32)
// of the 128x128 tile per stage. Accumulators: 4 x float16v = 64 VGPRs
// (half of round 12) -> target <=128 VGPR -> 4 waves/SIMD occupancy.
template<int KMID, bool RELU2, bool OUTF32>
__global__ __launch_bounds__(512) void fused_mlp(
        const unsigned short* __restrict__ Zin,
        const unsigned short* __restrict__ Wap, const float* __restrict__ ba,
        const unsigned short* __restrict__ Wbp, const float* __restrict__ bb,
        void* __restrict__ outp, int Mreal, int ntiles) {
    __shared__ unsigned short lds[16384];   // 32 KB: T tile, 2048 slots x 16 B
    const int tid = threadIdx.x;
    const int w = tid >> 6;        // 0..7
    const int l = tid & 63;
    const int lm = l & 31;
    const int lk = l >> 5;
    const int wr = w & 1;          // row half (64 rows)
    const int wc = w >> 1;         // col quarter (32 cols)
    constexpr int KS1 = 8;         // KIN = 128
    constexpr int KSB = KMID / 16; // Wb K-steps (total)
    constexpr int NH = KMID / 128; // halves

    for (int tile = blockIdx.x; tile < ntiles; tile += gridDim.x) {
        const long long R0 = (long long)tile * 128;
        const unsigned short* arow0 = Zin + (R0 + wr * 64 + lm) * 128 + lk * 8;
        const unsigned short* arow1 = arow0 + 32 * 128;

        float16v d0 = {}, d1 = {};

        for (int h = 0; h < NH; ++h) {
            __syncthreads();   // LDS reuse guard (prev half / prev tile reads done)

            // stage 1: Z @ Wa (T cols h*128 + wc*32 .. +32), bias+relu -> T in LDS
            {
                float16v c0 = {}, c1 = {};
                const int T1 = h * 4 + wc;
                const unsigned short* bp = Wap + ((long long)T1 * KS1 * 64 + l) * 8;
#pragma unroll
                for (int s = 0; s < KS1; ++s) {
                    short8 a0 = *(const short8*)(arow0 + s * 16);
                    short8 a1 = *(const short8*)(arow1 + s * 16);
                    short8 b = *(const short8*)(bp + (long long)s * 64 * 8);
                    c0 = __builtin_amdgcn_mfma_f32_32x32x16_bf16(a0, b, c0, 0, 0, 0);
                    c1 = __builtin_amdgcn_mfma_f32_32x32x16_bf16(a1, b, c1, 0, 0, 0);
                }
                auto wT = [&](float16v acc, int rbase, int cl) {
                    const float bv = ba[h * 128 + cl];
                    const int secT = cl >> 3;
                    const int cj = cl & 7;
#pragma unroll
                    for (int r = 0; r < 16; ++r) {
                        float v = fmaxf(acc[r] + bv, 0.f);
                        const int row = rbase + (r & 3) + 8 * (r >> 2);
                        lds[(secT * 128 + (row ^ (secT & 7))) * 8 + cj] = f2b(v);
                    }
                };
                wT(c0, wr * 64 + 4 * lk,      wc * 32 + lm);
                wT(c1, wr * 64 + 32 + 4 * lk, wc * 32 + lm);
            }
            __syncthreads();

            // stage 2: T @ Wb (k = h*128 .. +128), accumulate
            {
                const unsigned short* bp = Wbp + ((long long)wc * KSB * 64 + l) * 8;
#pragma unroll
                for (int s = 0; s < 8; ++s) {
                    const int sec = s * 2 + lk;
                    short8 a0 = *(const short8*)&lds[(sec * 128 + ((wr * 64 + lm) ^ (sec & 7))) * 8];
                    short8 a1 = *(const short8*)&lds[(sec * 128 + ((wr * 64 + 32 + lm) ^ (sec & 7))) * 8];
                    short8 b = *(const short8*)(bp + (long long)(h * 8 + s) * 64 * 8);
                    d0 = __builtin_amdgcn_mfma_f32_32x32x16_bf16(a0, b, d0, 0, 0, 0);
                    d1 = __builtin_amdgcn_mfma_f32_32x32x16_bf16(a1, b, d1, 0, 0, 0);
                }
            }
        }

        auto st = [&](float16v acc, int rbase, int col) {
            const float bv = bb[col];
#pragma unroll
            for (int r = 0; r < 16; ++r) {
                float v = acc[r] + bv;
                if (RELU2) v = fmaxf(v, 0.f);
                const long long row = R0 + rbase + (r & 3) + 8 * (r >> 2);
                if (OUTF32) {
                    if (row < Mreal) ((float*)outp)[row * 128 + col] = v;
                } else {
                    ((unsigned short*)outp)[row * 128 + col] = f2b(v);
                }
            }
        };
        st(d0, wr * 64 + 4 * lk,      wc * 32 + lm);
        st(d1, wr * 64 + 32 + 4 * lk, wc * 32 + lm);
    }
}

extern "C" void kernel_launch(void* const* d_in, const int* in_sizes, int n_in,
                              void* d_out, int out_size, void* d_ws, size_t ws_size,
                              hipStream_t stream) {
    const float* x    = (const float*)d_in[0];
    const int*   ei   = (const int*)d_in[1];
    const float* Wemb = (const float*)d_in[2];
    const float* eps1 = (const float*)d_in[3];
    const float* w1a  = (const float*)d_in[4];
    const float* b1a  = (const float*)d_in[5];
    const float* w1b  = (const float*)d_in[6];
    const float* b1b  = (const float*)d_in[7];
    const float* eps2 = (const float*)d_in[8];
    const float* w2a  = (const float*)d_in[9];
    const float* b2a  = (const float*)d_in[10];
    const float* w2b  = (const float*)d_in[11];
    const float* b2b  = (const float*)d_in[12];
    const float* eps3 = (const float*)d_in[13];
    const float* w3a  = (const float*)d_in[14];
    const float* b3a  = (const float*)d_in[15];
    const float* w3b  = (const float*)d_in[16];
    const float* b3b  = (const float*)d_in[17];

    const int N = in_sizes[0] / 64;   // 100000
    const int E = in_sizes[1] / 2;    // 1600000
    const int Mpad = ((N + 127) / 128) * 128;  // 100096
    const int NB = (N + BKT - 1) / BKT;   // 196
    const int G2 = 1024;
    const int PB = (E + G2 - 1) / G2;
    const int BH = NB * G2;

    char* ws = (char*)d_ws;
    size_t off = 0;
    auto alloc = [&](size_t bytes) -> void* {
        void* p = ws + off;
        off = (off + bytes + 255) & ~(size_t)255;
        return p;
    };
    unsigned short* Ha  = (unsigned short*)alloc((size_t)Mpad * 128 * 2);
    unsigned short* Hb2 = (unsigned short*)alloc((size_t)Mpad * 128 * 2);
    unsigned short* Zb  = (unsigned short*)alloc((size_t)Mpad * 128 * 2);
    unsigned short* pWe = (unsigned short*)alloc((size_t)64 * 128 * 2);
    unsigned short* p1a = (unsigned short*)alloc((size_t)128 * 128 * 2);
    unsigned short* p1b = (unsigned short*)alloc((size_t)128 * 128 * 2);
    unsigned short* p2a = (unsigned short*)alloc((size_t)128 * 256 * 2);
    unsigned short* p2b = (unsigned short*)alloc((size_t)256 * 128 * 2);
    unsigned short* p3a = (unsigned short*)alloc((size_t)128 * 256 * 2);
    unsigned short* p3b = (unsigned short*)alloc((size_t)256 * 128 * 2);
    int* offs = (int*)alloc((size_t)(N + 1) * 4);
    int* csr  = (int*)alloc((size_t)E * 4);
    unsigned int* staged = (unsigned int*)alloc((size_t)E * 4);
    int* bh   = (int*)alloc((size_t)BH * 4);
    int* bhs  = (int*)alloc((size_t)BH * 4);
    int* part = (int*)alloc(1024);
    int* boff = (int*)alloc(1024);
    int* flag = (int*)alloc(256);

    // ---- CSR build ----
    detect_i64_kernel<<<1, 64, 0, stream>>>((const unsigned int*)ei, flag);
    part_hist_kernel<<<G2, 256, 0, stream>>>(ei, flag, bh, E, NB, PB);
    const int G1 = (BH + 1023) / 1024;   // 196
    scan1_kernel<<<G1, 1024, 0, stream>>>(bh, bhs, part, BH);
    scan2_kernel<<<1, 256, 0, stream>>>(part, boff, G1);
    scan3g_kernel<<<G1, 1024, 0, stream>>>(bhs, boff, BH);
    part_scatter_kernel<<<G2, 256, 0, stream>>>(ei, flag, bhs, staged, E, NB, PB);
    csr_local_kernel<<<NB, 256, 0, stream>>>(staged, bhs, offs, csr, N, E, NB, G2);

    // ---- fused weight packing ----
    {
        PWAll P;
        const PW descs[7] = {
            {Wemb, pWe, 64, 128}, {w1a, p1a, 128, 128}, {w1b, p1b, 128, 128},
            {w2a, p2a, 128, 256}, {w2b, p2b, 256, 128}, {w3a, p3a, 128, 256},
            {w3b, p3b, 256, 128}};
        int c = 0;
        for (int k = 0; k < 7; ++k) {
            P.d[k] = descs[k];
            P.cum[k] = c;
            c += (descs[k].KOUT / 32) * (descs[k].K / 16) * 64;
        }
        P.cum[7] = c;
        packall_kernel<<<(c + 255) / 256, 256, 0, stream>>>(P);
    }

    const int MMB = Mpad / 128;      // 782 tiles
    const int AGB = (N + 15) / 16;   // 16 nodes per block
    const int PGRID = 512;           // 2 blocks/CU x 256 CUs (8 waves/block)

    // ---- embed: H = x @ W_embed (f32 read directly) ----
    mm_embed<<<MMB, 256, 0, stream>>>(x, pWe, Ha, N);

    // ---- layer 1: 128 -> 128(relu) -> 128 ----
    aggz_kernel<<<AGB, 256, 0, stream>>>(Ha, offs, csr, eps1, Zb, N);
    fused_mlp<128, false, false><<<PGRID, 512, 0, stream>>>(Zb, p1a, b1a, p1b, b1b, Hb2, N, MMB);

    // ---- layer 2: 128 -> 256(relu) -> 128(relu) ----
    aggz_kernel<<<AGB, 256, 0, stream>>>(Hb2, offs, csr, eps2, Zb, N);
    fused_mlp<256, true, false><<<PGRID, 512, 0, stream>>>(Zb, p2a, b2a, p2b, b2b, Ha, N, MMB);

    // ---- layer 3: 128 -> 256(relu) -> 128(relu), f32 out ----
    aggz_kernel<<<AGB, 256, 0, stream>>>(Ha, offs, csr, eps3, Zb, N);
    fused_mlp<256, true, true><<<PGRID, 512, 0, stream>>>(Zb, p3a, b3a, p3b, b3b, d_out, N, MMB);
}